// Round 7
// baseline (286.565 us; speedup 1.0000x reference)
//
#include <hip/hip_runtime.h>
#include <hip/hip_bf16.h>

// Problem constants
#define Bc 8
#define Tc 2048
#define Ec 256
#define Hc 2
#define HDc 128
#define Mrows (Bc*Tc)          // 16384
#define M2c 134

using bfx8  = __attribute__((ext_vector_type(8))) __bf16;
using f32x4 = __attribute__((ext_vector_type(4))) float;

__device__ __forceinline__ void gll16(const __bf16* g, __bf16* lds) {
    __builtin_amdgcn_global_load_lds(
        (const __attribute__((address_space(1))) unsigned int*)g,
        (__attribute__((address_space(3))) unsigned int*)lds, 16, 0, 0);
}

// ---------------- prep: convert weights to bf16, zero embsum ----------------
__global__ __launch_bounds__(256) void prep_k(const float* attn_w, const float* apw,
                                              const float* fcw, const float* mpw,
                                              __bf16* wb, float* embsum) {
    int i = blockIdx.x * 256 + threadIdx.x;
    if (i < 2048) embsum[i] = 0.f;
    if (i < 196608)       wb[i] = (__bf16)attn_w[i];
    else if (i < 262144)  wb[i] = (__bf16)apw[i - 196608];
    else if (i < 393216)  wb[i] = (__bf16)fcw[i - 262144];
    else if (i < 524288)  wb[i] = (__bf16)mpw[i - 393216];
}

// ---------------- embed + relu + LN1 ----------------
__global__ __launch_bounds__(256) void embed_ln_k(const float* X, const float* wpe,
                                                  const float* g, const float* bb,
                                                  __bf16* xres, __bf16* hb) {
    int m = blockIdx.x;
    int t = m & (Tc - 1);
    int e = threadIdx.x;
    float v = X[(size_t)m * Ec + e] + wpe[(size_t)t * Ec + e] + wpe[(size_t)(t >= 1024) * Ec + e];
    v = fmaxf(v, 0.f);
    xres[(size_t)m * Ec + e] = (__bf16)v;
    float s1 = v, s2 = v * v;
    #pragma unroll
    for (int o = 32; o; o >>= 1) { s1 += __shfl_xor(s1, o, 64); s2 += __shfl_xor(s2, o, 64); }
    __shared__ float a1[4], a2[4];
    int w = threadIdx.x >> 6;
    if ((threadIdx.x & 63) == 0) { a1[w] = s1; a2[w] = s2; }
    __syncthreads();
    float m1 = (a1[0] + a1[1] + a1[2] + a1[3]) * (1.f / 256.f);
    float m2 = (a2[0] + a2[1] + a2[2] + a2[3]) * (1.f / 256.f);
    float r = rsqrtf(m2 - m1 * m1 + 1e-5f);
    hb[(size_t)m * Ec + e] = (__bf16)((v - m1) * r * g[e] + bb[e]);
}

// ---------------- B^T GEMM (128x128 tile): EPI 0 = qkv scatter, EPI 2 = fc relu ----------------
template <int EPI>
__global__ __launch_bounds__(256) void gemm_bt(const __bf16* __restrict__ A,
                                               const __bf16* __restrict__ Bw,
                                               const float* __restrict__ bias,
                                               int N, int K,
                                               __bf16* __restrict__ outb,
                                               __bf16* __restrict__ Qb,
                                               __bf16* __restrict__ Kb,
                                               __bf16* __restrict__ Vb) {
    __shared__ __bf16 As[128 * 64];
    __shared__ __bf16 Bs[128 * 64];
    const int tid = threadIdx.x, w = tid >> 6, l = tid & 63;
    const int m0 = blockIdx.y * 128, n0 = blockIdx.x * 128;
    const int wr = w >> 1, wc = w & 1;
    const int quad = l >> 4, col15 = l & 15;

    f32x4 acc[4][4];
    f32x4 zz = {0.f, 0.f, 0.f, 0.f};
    #pragma unroll
    for (int i = 0; i < 4; i++)
        #pragma unroll
        for (int j = 0; j < 4; j++) acc[i][j] = zz;

    const int lrow = l >> 3;
    const int pbs  = l & 7;

    for (int kb = 0; kb < K; kb += 64) {
        #pragma unroll
        for (int it = 0; it < 4; it++) {
            int chunk = w * 4 + it;
            int row = chunk * 8 + lrow;
            int lb = pbs ^ (row & 7);
            gll16(A  + (size_t)(m0 + row) * K + kb + lb * 8, As + chunk * 512);
            gll16(Bw + (size_t)(n0 + row) * K + kb + lb * 8, Bs + chunk * 512);
        }
        __syncthreads();
        #pragma unroll
        for (int ks = 0; ks < 2; ks++) {
            bfx8 af[4], bfr[4];
            #pragma unroll
            for (int rt = 0; rt < 4; rt++) {
                int row = wr * 64 + rt * 16 + col15;
                int pb = (ks * 4 + quad) ^ (row & 7);
                af[rt] = *(const bfx8*)(As + row * 64 + pb * 8);
            }
            #pragma unroll
            for (int ct = 0; ct < 4; ct++) {
                int row = wc * 64 + ct * 16 + col15;
                int pb = (ks * 4 + quad) ^ (row & 7);
                bfr[ct] = *(const bfx8*)(Bs + row * 64 + pb * 8);
            }
            #pragma unroll
            for (int rt = 0; rt < 4; rt++)
                #pragma unroll
                for (int ct = 0; ct < 4; ct++)
                    acc[rt][ct] = __builtin_amdgcn_mfma_f32_16x16x32_bf16(af[rt], bfr[ct], acc[rt][ct], 0, 0, 0);
        }
        __syncthreads();
    }

    #pragma unroll
    for (int rt = 0; rt < 4; rt++)
        #pragma unroll
        for (int ct = 0; ct < 4; ct++) {
            int mgb = m0 + wr * 64 + rt * 16 + quad * 4;
            int ng  = n0 + wc * 64 + ct * 16 + col15;
            float bsv = bias[ng];
            #pragma unroll
            for (int r = 0; r < 4; r++) {
                float val = acc[rt][ct][r] + bsv;
                int mg = mgb + r;
                if constexpr (EPI == 0) {
                    val = fmaxf(val, 0.f);
                    int sel = ng >> 8;
                    int hh = (ng >> 7) & 1;
                    int d = ng & 127;
                    int bb = mg >> 11, tt = mg & (Tc - 1);
                    size_t idx = ((size_t)((bb * 2 + hh) * Tc + tt)) * HDc + d;
                    __bf16 bv = (__bf16)val;
                    if (sel == 0) Qb[idx] = bv;
                    else if (sel == 1) Kb[idx] = bv;
                    else Vb[idx] = bv;
                } else {
                    outb[(size_t)mg * 512 + ng] = (__bf16)fmaxf(val, 0.f);
                }
            }
        }
}

// ---------------- transpose V -> Vt[bh][d][t] ----------------
__global__ __launch_bounds__(256) void transpose_v(const unsigned short* Vb, unsigned short* Vt) {
    __shared__ unsigned short tile[64][66];
    int kt = blockIdx.x, dt = blockIdx.y, bh = blockIdx.z;
    int tid = threadIdx.x;
    int k0 = kt * 64, d0 = dt * 64;
    int rr = tid >> 4, cc = (tid & 15) * 4;
    #pragma unroll
    for (int p = 0; p < 4; p++) {
        int k = p * 16 + rr;
        const unsigned short* src = Vb + ((size_t)(bh * Tc + k0 + k)) * HDc + d0 + cc;
        ushort4 vv = *(const ushort4*)src;
        tile[k][cc] = vv.x; tile[k][cc + 1] = vv.y; tile[k][cc + 2] = vv.z; tile[k][cc + 3] = vv.w;
    }
    __syncthreads();
    #pragma unroll
    for (int p = 0; p < 4; p++) {
        int d = p * 16 + rr;
        unsigned short* dst = Vt + ((size_t)(bh * HDc + d0 + d)) * Tc + k0 + cc;
        ushort4 ov;
        ov.x = tile[cc][d]; ov.y = tile[cc + 1][d]; ov.z = tile[cc + 2][d]; ov.w = tile[cc + 3][d];
        *(ushort4*)dst = ov;
    }
}

// ---------------- causal relu attention v5 ----------------
// Merged triangle pair: block owns q-tiles A=pr and B=31-pr, processes BOTH against
// the same staged K/V tile (kt = loop index; A active while kt<nA). Units per block
// exactly 16/17 via c-split. Double-buffered K/V (loads issued AFTER the barrier so
// the implicit vmcnt(0) only drains loads that overlapped the previous compute).
// XCD-clustered bid decode: all 32 blocks of one bh land on one XCD (bid%8).
// Both halves write all A+B rows (zeros where untouched); Y = Y1 + Y2 downstream.
__global__ __launch_bounds__(256) void attn5_k(const __bf16* __restrict__ Qb,
                                               const __bf16* __restrict__ Kb,
                                               const __bf16* __restrict__ Vt,
                                               __bf16* __restrict__ Y1,
                                               __bf16* __restrict__ Y2) {
    __shared__ __bf16 Ks[2 * 64 * 128];   // 32KB, [buf][64 keys x 128 d]
    __shared__ __bf16 Vs[2 * 128 * 64];   // 32KB, [buf][128 d x 64 keys]
    __shared__ __bf16 Ss[2 * 64 * 64];    // 16KB: SsA | SsB
    int bid = blockIdx.x;                 // 512
    int lane8 = bid & 7, s = bid >> 3;    // s 0..63
    int bh = ((s & 1) << 3) | lane8;      // all 32 blocks of bh share bid%8 (XCD)
    int ph = s >> 1;                      // 0..31
    int pr = ph & 15, half = ph >> 4;
    int qtA = pr, qtB = 31 - pr;
    int Q0A = qtA * 64, Q0B = qtB * 64;
    int nA = pr + 1, nB = 32 - pr;
    int c = (nA >= 8) ? 8 : (16 - nA);    // units: half0 = 16, half1 = 17
    int js = half ? c : 0;
    int je = half ? nB : c;

    int tid = threadIdx.x, w = tid >> 6, l = tid & 63;
    int quad = l >> 4, col15 = l & 15;

    // ---- stage QA -> Ks[0], QB -> Vs[0]; read fragments ----
    {
        int lrow = l >> 4, pbs = l & 15;
        #pragma unroll
        for (int it = 0; it < 4; it++) {
            int chunk = w * 4 + it;
            int row = chunk * 4 + lrow;
            int lb = pbs ^ (row & 7);
            gll16(Qb + ((size_t)(bh * Tc + Q0A + row)) * HDc + lb * 8, Ks + chunk * 512);
            gll16(Qb + ((size_t)(bh * Tc + Q0B + row)) * HDc + lb * 8, Vs + chunk * 512);
        }
    }
    __syncthreads();
    bfx8 qfA[4], qfB[4];
    #pragma unroll
    for (int ks = 0; ks < 4; ks++) {
        int row = w * 16 + col15;
        int pb = (ks * 4 + quad) ^ (row & 7);
        qfA[ks] = *(const bfx8*)(Ks + row * 128 + pb * 8);
        qfB[ks] = *(const bfx8*)(Vs + row * 128 + pb * 8);
    }
    __syncthreads();   // all waves done reading before tile loads overwrite buf0

    f32x4 zz = {0.f, 0.f, 0.f, 0.f};
    f32x4 yaccA[8], yaccB[8];
    #pragma unroll
    for (int i = 0; i < 8; i++) { yaccA[i] = zz; yaccB[i] = zz; }

    const int lrowK = l >> 4, pbsK = l & 15;
    const int lrowV = l >> 3, pbsV = l & 7;
    #define LOAD_TILE(kt, buf)                                                            \
        {                                                                                 \
            _Pragma("unroll")                                                             \
            for (int it = 0; it < 4; it++) {                                              \
                int chunk = w * 4 + it;                                                   \
                int row = chunk * 4 + lrowK;                                              \
                int lb = pbsK ^ (row & 7);                                                \
                gll16(Kb + ((size_t)(bh * Tc + (kt) * 64 + row)) * HDc + lb * 8,          \
                      Ks + (buf) * 8192 + chunk * 512);                                   \
            }                                                                             \
            _Pragma("unroll")                                                             \
            for (int it = 0; it < 4; it++) {                                              \
                int chunk = w * 4 + it;                                                   \
                int row = chunk * 8 + lrowV;                                              \
                int lb = pbsV ^ (row & 7);                                                \
                gll16(Vt + ((size_t)(bh * HDc + row)) * Tc + (kt) * 64 + lb * 8,          \
                      Vs + (buf) * 8192 + chunk * 512);                                   \
            }                                                                             \
        }

    LOAD_TILE(js, js & 1);   // prime

    for (int j = js; j < je; j++) {
        __syncthreads();     // drains tile-j loads (issued last iter, overlapped compute)
        if (j + 1 < je) LOAD_TILE(j + 1, (j + 1) & 1);
        const __bf16* Kc = Ks + (j & 1) * 8192;
        const __bf16* Vc = Vs + (j & 1) * 8192;
        int doA = (j < nA);

        // ---- S = Q K^T for B (and A if active), shared kf reads ----
        f32x4 saccA[4], saccB[4];
        #pragma unroll
        for (int i = 0; i < 4; i++) { saccA[i] = zz; saccB[i] = zz; }
        #pragma unroll
        for (int ks = 0; ks < 4; ks++) {
            bfx8 kf[4];
            #pragma unroll
            for (int ct = 0; ct < 4; ct++) {
                int row = ct * 16 + col15;
                int pb = (ks * 4 + quad) ^ (row & 7);
                kf[ct] = *(const bfx8*)(Kc + row * 128 + pb * 8);
            }
            #pragma unroll
            for (int ct = 0; ct < 4; ct++)
                saccB[ct] = __builtin_amdgcn_mfma_f32_16x16x32_bf16(qfB[ks], kf[ct], saccB[ct], 0, 0, 0);
            if (doA) {
                #pragma unroll
                for (int ct = 0; ct < 4; ct++)
                    saccA[ct] = __builtin_amdgcn_mfma_f32_16x16x32_bf16(qfA[ks], kf[ct], saccA[ct], 0, 0, 0);
            }
        }

        // ---- mask + relu -> Ss (own rows, same-wave ordering: no barrier) ----
        #pragma unroll
        for (int ct = 0; ct < 4; ct++) {
            int kl = ct * 16 + col15;
            int kg = j * 64 + kl;
            int blk = kl >> 3, off = kl & 7;
            #pragma unroll
            for (int r = 0; r < 4; r++) {
                int qlw = w * 16 + quad * 4 + r;
                int pb = blk ^ (qlw & 7);
                float vB = (kg <= Q0B + qlw) ? fmaxf(saccB[ct][r], 0.f) : 0.f;
                Ss[4096 + qlw * 64 + pb * 8 + off] = (__bf16)vB;
                if (doA) {
                    float vA = (kg <= Q0A + qlw) ? fmaxf(saccA[ct][r], 0.f) : 0.f;
                    Ss[qlw * 64 + pb * 8 + off] = (__bf16)vA;
                }
            }
        }

        // ---- Y += S * V, shared vf reads ----
        #pragma unroll
        for (int ks = 0; ks < 2; ks++) {
            int rowS = w * 16 + col15;
            int pbS = (ks * 4 + quad) ^ (rowS & 7);
            bfx8 sfB = *(const bfx8*)(Ss + 4096 + rowS * 64 + pbS * 8);
            bfx8 sfA = *(const bfx8*)(Ss + rowS * 64 + pbS * 8);
            #pragma unroll
            for (int dt = 0; dt < 8; dt++) {
                int row = dt * 16 + col15;
                int pb = (ks * 4 + quad) ^ (row & 7);
                bfx8 vf = *(const bfx8*)(Vc + row * 64 + pb * 8);
                yaccB[dt] = __builtin_amdgcn_mfma_f32_16x16x32_bf16(sfB, vf, yaccB[dt], 0, 0, 0);
                if (doA)
                    yaccA[dt] = __builtin_amdgcn_mfma_f32_16x16x32_bf16(sfA, vf, yaccA[dt], 0, 0, 0);
            }
        }
    }

    __bf16* Yp = half ? Y2 : Y1;
    int b = bh >> 1, h = bh & 1;
    const float sc = 0.08838834764831845f;  // 1/sqrt(128)
    #pragma unroll
    for (int dt = 0; dt < 8; dt++) {
        int d = dt * 16 + col15;
        #pragma unroll
        for (int r = 0; r < 4; r++) {
            int qa = Q0A + w * 16 + quad * 4 + r;
            int qb2 = Q0B + w * 16 + quad * 4 + r;
            Yp[((size_t)(b * Tc + qa)) * Ec + h * HDc + d] = (__bf16)(yaccA[dt][r] * sc);
            Yp[((size_t)(b * Tc + qb2)) * Ec + h * HDc + d] = (__bf16)(yaccB[dt][r] * sc);
        }
    }
}

// ---------------- fused GEMM (64x256 tile) + LN epilogue ----------------
// MODE 0: attnproj — A = Y1 + Y2 combined during staging;
//         x2 = resid + C + bias; out1 = bf16(x2); out2 = LN(x2; g,b)
// MODE 1: mlpproj  — A staged via gll16; x3 = relu(resid + C + bias);
//         xf = relu(LN(x3)); column-reduce xf into embsum
template <int MODE>
__global__ __launch_bounds__(256) void gemm_ln(const __bf16* __restrict__ A,
                                               const __bf16* __restrict__ A2,
                                               const __bf16* __restrict__ W,
                                               const float* __restrict__ bias, int K,
                                               const __bf16* __restrict__ resid,
                                               const float* __restrict__ g,
                                               const float* __restrict__ bb,
                                               __bf16* __restrict__ out1,
                                               __bf16* __restrict__ out2,
                                               float* __restrict__ embsum) {
    __shared__ __bf16 As[64 * 64];     // 8KB
    __shared__ __bf16 Bs[256 * 64];    // 32KB
    __shared__ float cs[256];
    const int tid = threadIdx.x, w = tid >> 6, l = tid & 63;
    const int m0 = blockIdx.x * 64;
    const int quad = l >> 4, col15 = l & 15;
    const int lrow = l >> 3, pbs = l & 7;

    f32x4 acc[16];
    f32x4 zz = {0.f, 0.f, 0.f, 0.f};
    #pragma unroll
    for (int i = 0; i < 16; i++) acc[i] = zz;
    if (MODE == 1) { cs[tid] = 0.f; }

    for (int kb = 0; kb < K; kb += 64) {
        if (MODE == 0) {
            // A = Y1 + Y2, staged via registers
            bfx8 av[2];
            int rows[2], blks[2];
            #pragma unroll
            for (int it = 0; it < 2; it++) {
                int idx = it * 256 + tid;
                int row = idx >> 3, blk = idx & 7;
                rows[it] = row; blks[it] = blk;
                int mg = m0 + row;
                bfx8 a1 = *(const bfx8*)(A  + (size_t)mg * K + kb + blk * 8);
                bfx8 a2 = *(const bfx8*)(A2 + (size_t)mg * K + kb + blk * 8);
                #pragma unroll
                for (int jj = 0; jj < 8; jj++) a1[jj] = (__bf16)((float)a1[jj] + (float)a2[jj]);
                av[it] = a1;
            }
            __syncthreads();
            #pragma unroll
            for (int it = 0; it < 2; it++) {
                int row = rows[it];
                int pb = blks[it] ^ (row & 7);
                *(bfx8*)(As + row * 64 + pb * 8) = av[it];
            }
        } else {
            __syncthreads();
            #pragma unroll
            for (int it = 0; it < 2; it++) {
                int chunk = w * 2 + it;
                int row = chunk * 8 + lrow;
                int lb = pbs ^ (row & 7);
                gll16(A + (size_t)(m0 + row) * K + kb + lb * 8, As + chunk * 512);
            }
        }
        #pragma unroll
        for (int it = 0; it < 8; it++) {   // B: 32 chunks (all 256 n-rows)
            int chunk = w * 8 + it;
            int row = chunk * 8 + lrow;
            int lb = pbs ^ (row & 7);
            gll16(W + (size_t)row * K + kb + lb * 8, Bs + chunk * 512);
        }
        __syncthreads();
        #pragma unroll
        for (int ks = 0; ks < 2; ks++) {
            int arow = w * 16 + col15;
            int apb = (ks * 4 + quad) ^ (arow & 7);
            bfx8 af = *(const bfx8*)(As + arow * 64 + apb * 8);
            #pragma unroll
            for (int ct = 0; ct < 16; ct++) {
                int brow = ct * 16 + col15;
                int bpb = (ks * 4 + quad) ^ (brow & 7);
                bfx8 bf = *(const bfx8*)(Bs + brow * 64 + bpb * 8);
                acc[ct] = __builtin_amdgcn_mfma_f32_16x16x32_bf16(af, bf, acc[ct], 0, 0, 0);
            }
        }
    }
    __syncthreads();

    float xv[16][4];
    #pragma unroll
    for (int ct = 0; ct < 16; ct++) {
        int ng = ct * 16 + col15;
        float bsv = bias[ng];
        #pragma unroll
        for (int r = 0; r < 4; r++) {
            int mg = m0 + w * 16 + quad * 4 + r;
            float v = acc[ct][r] + bsv + (float)resid[(size_t)mg * 256 + ng];
            if (MODE == 1) v = fmaxf(v, 0.f);
            xv[ct][r] = v;
        }
    }
    if (MODE == 0) {
        #pragma unroll
        for (int ct = 0; ct < 16; ct++) {
            int ng = ct * 16 + col15;
            #pragma unroll
            for (int r = 0; r < 4; r++) {
                int mg = m0 + w * 16 + quad * 4 + r;
                out1[(size_t)mg * 256 + ng] = (__bf16)xv[ct][r];
            }
        }
    }
    float s1[4], s2[4];
    #pragma unroll
    for (int r = 0; r < 4; r++) {
        float a = 0.f, b2 = 0.f;
        #pragma unroll
        for (int ct = 0; ct < 16; ct++) { a += xv[ct][r]; b2 += xv[ct][r] * xv[ct][r]; }
        #pragma unroll
        for (int o = 1; o < 16; o <<= 1) { a += __shfl_xor(a, o, 64); b2 += __shfl_xor(b2, o, 64); }
        s1[r] = a; s2[r] = b2;
    }
    float colsum[16];
    #pragma unroll
    for (int ct = 0; ct < 16; ct++) colsum[ct] = 0.f;
    #pragma unroll
    for (int r = 0; r < 4; r++) {
        float mu = s1[r] * (1.f / 256.f);
        float var = s2[r] * (1.f / 256.f) - mu * mu;
        float rs = rsqrtf(var + 1e-5f);
        #pragma unroll
        for (int ct = 0; ct < 16; ct++) {
            int ng = ct * 16 + col15;
            float h = (xv[ct][r] - mu) * rs * g[ng] + bb[ng];
            if (MODE == 1) {
                colsum[ct] += fmaxf(h, 0.f);
            } else {
                int mg = m0 + w * 16 + quad * 4 + r;
                out2[(size_t)mg * 256 + ng] = (__bf16)h;
            }
        }
    }
    if (MODE == 1) {
        #pragma unroll
        for (int ct = 0; ct < 16; ct++) {
            colsum[ct] += __shfl_xor(colsum[ct], 16, 64);
            colsum[ct] += __shfl_xor(colsum[ct], 32, 64);
        }
        if (quad == 0) {
            #pragma unroll
            for (int ct = 0; ct < 16; ct++)
                atomicAdd(&cs[ct * 16 + col15], colsum[ct]);
        }
        __syncthreads();
        atomicAdd(&embsum[(m0 >> 11) * 256 + tid], cs[tid]);
    }
}

// ---------------- final: emb, logits, losses, outputs — FLOAT32 output ----------------
__global__ __launch_bounds__(256) void final_k(const float* embsum, const float* Yt,
                                               const float* head_w, const float* head_b,
                                               float* out) {
    __shared__ float semb[2048];
    __shared__ float slog[1072];
    int tid = threadIdx.x;
    for (int i = tid; i < 2048; i += 256) semb[i] = embsum[i] * (1.f / 2048.f);
    __syncthreads();
    float part1 = 0.f;
    for (int idx = tid; idx < 1072; idx += 256) {
        int b = idx / M2c, n = idx - b * M2c;
        float acc = head_b[n];
        const float* wn = head_w + (size_t)n * Ec;
        const float* e = semb + b * Ec;
        #pragma unroll 8
        for (int k = 0; k < Ec; k++) acc += e[k] * wn[k];
        acc = fmaxf(acc, 0.f);
        slog[idx] = acc;
        float d = acc - Yt[idx];
        part1 += d * d;
    }
    float part3 = 0.f;
    for (int idx = tid; idx < 1024; idx += 256) {
        int b = idx >> 7, i = idx & 127;
        float d = semb[b * Ec + i] - semb[b * Ec + 128 + i];
        part3 += d * d;
    }
    #pragma unroll
    for (int o = 32; o; o >>= 1) { part1 += __shfl_xor(part1, o, 64); part3 += __shfl_xor(part3, o, 64); }
    __shared__ float r1[4], r3[4];
    int w = tid >> 6;
    if ((tid & 63) == 0) { r1[w] = part1; r3[w] = part3; }
    __syncthreads();
    float l1 = sqrtf((r1[0] + r1[1] + r1[2] + r1[3]) / 1072.f);
    float l3 = sqrtf((r3[0] + r3[1] + r3[2] + r3[3]) / 1024.f);
    for (int idx = tid; idx < 1024; idx += 256) {
        int b = idx >> 7, i = idx & 127;
        out[idx]        = semb[b * Ec + i];
        out[1024 + idx] = semb[b * Ec + 128 + i];
    }
    if (tid == 0) {
        out[2048] = 50.f * l1 + l3;
        out[2049] = l1;
        out[2050] = l3;
    }
    for (int idx = tid; idx < 1072; idx += 256) out[2051 + idx] = slog[idx];
}

extern "C" void kernel_launch(void* const* d_in, const int* in_sizes, int n_in,
                              void* d_out, int out_size, void* d_ws, size_t ws_size,
                              hipStream_t stream) {
    const float* X        = (const float*)d_in[0];
    const float* Yt       = (const float*)d_in[1];
    const float* wpe      = (const float*)d_in[2];
    const float* ln1_g    = (const float*)d_in[3];
    const float* ln1_b    = (const float*)d_in[4];
    const float* attn_w   = (const float*)d_in[5];
    const float* attn_b   = (const float*)d_in[6];
    const float* apw      = (const float*)d_in[7];
    const float* apb      = (const float*)d_in[8];
    const float* ln2_g    = (const float*)d_in[9];
    const float* ln2_b    = (const float*)d_in[10];
    const float* fcw      = (const float*)d_in[11];
    const float* fcb      = (const float*)d_in[12];
    const float* mpw      = (const float*)d_in[13];
    const float* mpb      = (const float*)d_in[14];
    const float* lnf_g    = (const float*)d_in[15];
    const float* lnf_b    = (const float*)d_in[16];
    const float* head_w   = (const float*)d_in[17];
    const float* head_b   = (const float*)d_in[18];

    char* ws = (char*)d_ws;
    const size_t MB = 1048576;
    __bf16* xres   = (__bf16*)(ws + 0 * MB);    // 8 MB
    __bf16* hb     = (__bf16*)(ws + 8 * MB);    // 8 MB
    __bf16* Qb     = (__bf16*)(ws + 16 * MB);   // 8 MB; later x2
    __bf16* Kb     = (__bf16*)(ws + 24 * MB);   // 8 MB; later h2
    __bf16* Vb     = (__bf16*)(ws + 32 * MB);   // 8 MB
    __bf16* Vt     = (__bf16*)(ws + 40 * MB);   // 8 MB
    __bf16* Y1     = (__bf16*)(ws + 48 * MB);   // 8 MB
    __bf16* Y2     = (__bf16*)(ws + 56 * MB);   // 8 MB
    __bf16* fcout  = (__bf16*)(ws + 64 * MB);   // 16 MB
    __bf16* wb     = (__bf16*)(ws + 80 * MB);   // 1 MB
    float*  embsum = (float*)(ws + 81 * MB);    // 8 KB

    __bf16* x2   = Qb;     // Qb dead after attn
    __bf16* h2   = Kb;     // Kb dead after attn

    __bf16* wqkv = wb;
    __bf16* wap  = wb + 196608;
    __bf16* wfc  = wb + 262144;
    __bf16* wmp  = wb + 393216;

    prep_k<<<2048, 256, 0, stream>>>(attn_w, apw, fcw, mpw, wb, embsum);
    embed_ln_k<<<Mrows, 256, 0, stream>>>(X, wpe, ln1_g, ln1_b, xres, hb);
    gemm_bt<0><<<dim3(6, 128), 256, 0, stream>>>(hb, wqkv, attn_b, 768, 256,
                                                 nullptr, Qb, Kb, Vb);
    transpose_v<<<dim3(32, 2, 16), 256, 0, stream>>>((const unsigned short*)Vb, (unsigned short*)Vt);
    attn5_k<<<512, 256, 0, stream>>>(Qb, Kb, Vt, Y1, Y2);
    gemm_ln<0><<<256, 256, 0, stream>>>(Y1, Y2, wap, apb, 256, xres, ln2_g, ln2_b,
                                        x2, h2, nullptr);
    gemm_bt<2><<<dim3(4, 128), 256, 0, stream>>>(h2, wfc, fcb, 512, 256,
                                                 fcout, nullptr, nullptr, nullptr);
    gemm_ln<1><<<256, 256, 0, stream>>>(fcout, nullptr, wmp, mpb, 512, x2, lnf_g, lnf_b,
                                        nullptr, nullptr, embsum);
    final_k<<<1, 256, 0, stream>>>(embsum, Yt, head_w, head_b, (float*)d_out);
}

// Round 8
// 256.590 us; speedup vs baseline: 1.1168x; 1.1168x over previous
//
#include <hip/hip_runtime.h>
#include <hip/hip_bf16.h>

// Problem constants
#define Bc 8
#define Tc 2048
#define Ec 256
#define Hc 2
#define HDc 128
#define Mrows (Bc*Tc)          // 16384
#define M2c 134

using bfx8  = __attribute__((ext_vector_type(8))) __bf16;
using f32x4 = __attribute__((ext_vector_type(4))) float;

__device__ __forceinline__ void gll16(const __bf16* g, __bf16* lds) {
    __builtin_amdgcn_global_load_lds(
        (const __attribute__((address_space(1))) unsigned int*)g,
        (__attribute__((address_space(3))) unsigned int*)lds, 16, 0, 0);
}

// ---------------- prep: convert weights to bf16, zero embsum ----------------
__global__ __launch_bounds__(256) void prep_k(const float* attn_w, const float* apw,
                                              const float* fcw, const float* mpw,
                                              __bf16* wb, float* embsum) {
    int i = blockIdx.x * 256 + threadIdx.x;
    if (i < 2048) embsum[i] = 0.f;
    if (i < 196608)       wb[i] = (__bf16)attn_w[i];
    else if (i < 262144)  wb[i] = (__bf16)apw[i - 196608];
    else if (i < 393216)  wb[i] = (__bf16)fcw[i - 262144];
    else if (i < 524288)  wb[i] = (__bf16)mpw[i - 393216];
}

// ---------------- embed + relu + LN1 ----------------
__global__ __launch_bounds__(256) void embed_ln_k(const float* X, const float* wpe,
                                                  const float* g, const float* bb,
                                                  __bf16* xres, __bf16* hb) {
    int m = blockIdx.x;
    int t = m & (Tc - 1);
    int e = threadIdx.x;
    float v = X[(size_t)m * Ec + e] + wpe[(size_t)t * Ec + e] + wpe[(size_t)(t >= 1024) * Ec + e];
    v = fmaxf(v, 0.f);
    xres[(size_t)m * Ec + e] = (__bf16)v;
    float s1 = v, s2 = v * v;
    #pragma unroll
    for (int o = 32; o; o >>= 1) { s1 += __shfl_xor(s1, o, 64); s2 += __shfl_xor(s2, o, 64); }
    __shared__ float a1[4], a2[4];
    int w = threadIdx.x >> 6;
    if ((threadIdx.x & 63) == 0) { a1[w] = s1; a2[w] = s2; }
    __syncthreads();
    float m1 = (a1[0] + a1[1] + a1[2] + a1[3]) * (1.f / 256.f);
    float m2 = (a2[0] + a2[1] + a2[2] + a2[3]) * (1.f / 256.f);
    float r = rsqrtf(m2 - m1 * m1 + 1e-5f);
    hb[(size_t)m * Ec + e] = (__bf16)((v - m1) * r * g[e] + bb[e]);
}

// ---------------- B^T GEMM (128x128 tile): EPI 0 = qkv scatter, EPI 2 = fc relu ----------------
template <int EPI>
__global__ __launch_bounds__(256) void gemm_bt(const __bf16* __restrict__ A,
                                               const __bf16* __restrict__ Bw,
                                               const float* __restrict__ bias,
                                               int N, int K,
                                               __bf16* __restrict__ outb,
                                               __bf16* __restrict__ Qb,
                                               __bf16* __restrict__ Kb,
                                               __bf16* __restrict__ Vb) {
    __shared__ __bf16 As[128 * 64];
    __shared__ __bf16 Bs[128 * 64];
    const int tid = threadIdx.x, w = tid >> 6, l = tid & 63;
    const int m0 = blockIdx.y * 128, n0 = blockIdx.x * 128;
    const int wr = w >> 1, wc = w & 1;
    const int quad = l >> 4, col15 = l & 15;

    f32x4 acc[4][4];
    f32x4 zz = {0.f, 0.f, 0.f, 0.f};
    #pragma unroll
    for (int i = 0; i < 4; i++)
        #pragma unroll
        for (int j = 0; j < 4; j++) acc[i][j] = zz;

    const int lrow = l >> 3;
    const int pbs  = l & 7;

    for (int kb = 0; kb < K; kb += 64) {
        #pragma unroll
        for (int it = 0; it < 4; it++) {
            int chunk = w * 4 + it;
            int row = chunk * 8 + lrow;
            int lb = pbs ^ (row & 7);
            gll16(A  + (size_t)(m0 + row) * K + kb + lb * 8, As + chunk * 512);
            gll16(Bw + (size_t)(n0 + row) * K + kb + lb * 8, Bs + chunk * 512);
        }
        __syncthreads();
        #pragma unroll
        for (int ks = 0; ks < 2; ks++) {
            bfx8 af[4], bfr[4];
            #pragma unroll
            for (int rt = 0; rt < 4; rt++) {
                int row = wr * 64 + rt * 16 + col15;
                int pb = (ks * 4 + quad) ^ (row & 7);
                af[rt] = *(const bfx8*)(As + row * 64 + pb * 8);
            }
            #pragma unroll
            for (int ct = 0; ct < 4; ct++) {
                int row = wc * 64 + ct * 16 + col15;
                int pb = (ks * 4 + quad) ^ (row & 7);
                bfr[ct] = *(const bfx8*)(Bs + row * 64 + pb * 8);
            }
            #pragma unroll
            for (int rt = 0; rt < 4; rt++)
                #pragma unroll
                for (int ct = 0; ct < 4; ct++)
                    acc[rt][ct] = __builtin_amdgcn_mfma_f32_16x16x32_bf16(af[rt], bfr[ct], acc[rt][ct], 0, 0, 0);
        }
        __syncthreads();
    }

    #pragma unroll
    for (int rt = 0; rt < 4; rt++)
        #pragma unroll
        for (int ct = 0; ct < 4; ct++) {
            int mgb = m0 + wr * 64 + rt * 16 + quad * 4;
            int ng  = n0 + wc * 64 + ct * 16 + col15;
            float bsv = bias[ng];
            #pragma unroll
            for (int r = 0; r < 4; r++) {
                float val = acc[rt][ct][r] + bsv;
                int mg = mgb + r;
                if constexpr (EPI == 0) {
                    val = fmaxf(val, 0.f);
                    int sel = ng >> 8;
                    int hh = (ng >> 7) & 1;
                    int d = ng & 127;
                    int bb = mg >> 11, tt = mg & (Tc - 1);
                    size_t idx = ((size_t)((bb * 2 + hh) * Tc + tt)) * HDc + d;
                    __bf16 bv = (__bf16)val;
                    if (sel == 0) Qb[idx] = bv;
                    else if (sel == 1) Kb[idx] = bv;
                    else Vb[idx] = bv;
                } else {
                    outb[(size_t)mg * 512 + ng] = (__bf16)fmaxf(val, 0.f);
                }
            }
        }
}

// ---------------- transpose V -> Vt[bh][d][t] ----------------
__global__ __launch_bounds__(256) void transpose_v(const unsigned short* Vb, unsigned short* Vt) {
    __shared__ unsigned short tile[64][66];
    int kt = blockIdx.x, dt = blockIdx.y, bh = blockIdx.z;
    int tid = threadIdx.x;
    int k0 = kt * 64, d0 = dt * 64;
    int rr = tid >> 4, cc = (tid & 15) * 4;
    #pragma unroll
    for (int p = 0; p < 4; p++) {
        int k = p * 16 + rr;
        const unsigned short* src = Vb + ((size_t)(bh * Tc + k0 + k)) * HDc + d0 + cc;
        ushort4 vv = *(const ushort4*)src;
        tile[k][cc] = vv.x; tile[k][cc + 1] = vv.y; tile[k][cc + 2] = vv.z; tile[k][cc + 3] = vv.w;
    }
    __syncthreads();
    #pragma unroll
    for (int p = 0; p < 4; p++) {
        int d = p * 16 + rr;
        unsigned short* dst = Vt + ((size_t)(bh * HDc + d0 + d)) * Tc + k0 + cc;
        ushort4 ov;
        ov.x = tile[cc][d]; ov.y = tile[cc + 1][d]; ov.z = tile[cc + 2][d]; ov.w = tile[cc + 3][d];
        *(ushort4*)dst = ov;
    }
}

// ---------------- causal relu attention v6: fine-grained, occupancy-driven ----------------
// One 64-row q-tile per block, keys chunked into <=8 kt-tiles. Grid 1280 =
// 16 bh x 80 chunks; per-bh chunk count: qt 0-7:1, 8-15:2, 16-23:3, 24-31:4.
// LDS 40KB (Ks16+Vs16+Ss8, Ss reused same-wave in order) -> 4 blocks/CU.
// Partial Y for chunk c goes to Ys[c]; downstream sums n=ceil((qt+1)/8) buffers.
__global__ __launch_bounds__(256, 4) void attn6_k(const __bf16* __restrict__ Qb,
                                                  const __bf16* __restrict__ Kb,
                                                  const __bf16* __restrict__ Vt,
                                                  __bf16* __restrict__ Y1,
                                                  __bf16* __restrict__ Y2,
                                                  __bf16* __restrict__ Y3,
                                                  __bf16* __restrict__ Y4) {
    __shared__ __bf16 Ks[64 * 128];   // 16KB: Q staging, then K tiles
    __shared__ __bf16 Vs[128 * 64];   // 16KB
    __shared__ __bf16 Ss[64 * 64];    // 8KB, per-wave-private rows
    int bid = blockIdx.x;             // 0..1279
    int lane8 = bid & 7;
    int s = bid >> 3;                 // 0..159
    int bh = ((s & 1) << 3) | lane8;  // blocks of one bh share bid%8 (XCD cluster)
    int f = s >> 1;                   // 0..79
    int qt, ch;
    if (f < 8)       { qt = f;                    ch = 0; }
    else if (f < 24) { qt = 8 + ((f - 8) >> 1);   ch = (f - 8) & 1; }
    else if (f < 48) { int r = f - 24; int d3 = r / 3; qt = 16 + d3; ch = r - 3 * d3; }
    else             { int r = f - 48; qt = 24 + (r >> 2); ch = r & 3; }
    int Q0 = qt * 64;
    int kts = ch * 8;
    int kte = min(kts + 8, qt + 1);

    int tid = threadIdx.x, w = tid >> 6, l = tid & 63;
    int quad = l >> 4, col15 = l & 15;
    const int lrowK = l >> 4, pbsK = l & 15;   // 64x128 tiles: 4 rows/1KB chunk
    const int lrowV = l >> 3, pbsV = l & 7;    // 128x64 tiles: 8 rows/1KB chunk

    // ---- stage Q tile into Ks, read fragments ----
    #pragma unroll
    for (int it = 0; it < 4; it++) {
        int chunk = w * 4 + it;
        int row = chunk * 4 + lrowK;
        int lb = pbsK ^ (row & 7);
        gll16(Qb + ((size_t)(bh * Tc + Q0 + row)) * HDc + lb * 8, Ks + chunk * 512);
    }
    __syncthreads();
    bfx8 qf[4];
    #pragma unroll
    for (int ks = 0; ks < 4; ks++) {
        int row = w * 16 + col15;
        int pb = (ks * 4 + quad) ^ (row & 7);
        qf[ks] = *(const bfx8*)(Ks + row * 128 + pb * 8);
    }

    f32x4 zz = {0.f, 0.f, 0.f, 0.f};
    f32x4 yacc[8];
    #pragma unroll
    for (int i = 0; i < 8; i++) yacc[i] = zz;

    for (int kt = kts; kt < kte; kt++) {
        __syncthreads();   // prior iter (or Q-frag) reads done
        #pragma unroll
        for (int it = 0; it < 4; it++) {
            int chunk = w * 4 + it;
            int rowK = chunk * 4 + lrowK;
            int lbK = pbsK ^ (rowK & 7);
            gll16(Kb + ((size_t)(bh * Tc + kt * 64 + rowK)) * HDc + lbK * 8, Ks + chunk * 512);
            int rowV = chunk * 8 + lrowV;
            int lbV = pbsV ^ (rowV & 7);
            gll16(Vt + ((size_t)(bh * HDc + rowV)) * Tc + kt * 64 + lbV * 8, Vs + chunk * 512);
        }
        __syncthreads();   // drain

        // ---- S = Q K^T : 16 q-rows per wave x 64 keys ----
        f32x4 sacc[4];
        #pragma unroll
        for (int i = 0; i < 4; i++) sacc[i] = zz;
        #pragma unroll
        for (int ks = 0; ks < 4; ks++) {
            #pragma unroll
            for (int ct = 0; ct < 4; ct++) {
                int row = ct * 16 + col15;
                int pb = (ks * 4 + quad) ^ (row & 7);
                bfx8 kf = *(const bfx8*)(Ks + row * 128 + pb * 8);
                sacc[ct] = __builtin_amdgcn_mfma_f32_16x16x32_bf16(qf[ks], kf, sacc[ct], 0, 0, 0);
            }
        }

        // ---- mask + relu -> Ss (own rows; same-wave in-order LDS, no barrier) ----
        #pragma unroll
        for (int ct = 0; ct < 4; ct++) {
            int kl = ct * 16 + col15;
            int kg = kt * 64 + kl;
            int blk = kl >> 3, off = kl & 7;
            #pragma unroll
            for (int r = 0; r < 4; r++) {
                int qlw = w * 16 + quad * 4 + r;
                float val = (kg <= Q0 + qlw) ? fmaxf(sacc[ct][r], 0.f) : 0.f;
                int pb = blk ^ (qlw & 7);
                Ss[qlw * 64 + pb * 8 + off] = (__bf16)val;
            }
        }

        // ---- Y += S * V ----
        #pragma unroll
        for (int ks = 0; ks < 2; ks++) {
            int rowS = w * 16 + col15;
            int pbS = (ks * 4 + quad) ^ (rowS & 7);
            bfx8 sf = *(const bfx8*)(Ss + rowS * 64 + pbS * 8);
            #pragma unroll
            for (int dt = 0; dt < 8; dt++) {
                int row = dt * 16 + col15;
                int pb = (ks * 4 + quad) ^ (row & 7);
                bfx8 vf = *(const bfx8*)(Vs + row * 64 + pb * 8);
                yacc[dt] = __builtin_amdgcn_mfma_f32_16x16x32_bf16(sf, vf, yacc[dt], 0, 0, 0);
            }
        }
    }

    __bf16* Yp = (ch == 0) ? Y1 : (ch == 1) ? Y2 : (ch == 2) ? Y3 : Y4;
    int b = bh >> 1, h = bh & 1;
    const float sc = 0.08838834764831845f;  // 1/sqrt(128)
    #pragma unroll
    for (int dt = 0; dt < 8; dt++) {
        int d = dt * 16 + col15;
        #pragma unroll
        for (int r = 0; r < 4; r++) {
            int q = Q0 + w * 16 + quad * 4 + r;
            Yp[((size_t)(b * Tc + q)) * Ec + h * HDc + d] = (__bf16)(yacc[dt][r] * sc);
        }
    }
}

// ---------------- fused GEMM (64x256 tile) + LN epilogue ----------------
// MODE 0: attnproj — A = sum of n Y-partials (n = ceil((qt+1)/8)) during staging;
//         x2 = resid + C + bias; out1 = bf16(x2); out2 = LN(x2; g,b)
// MODE 1: mlpproj  — A staged via gll16; x3 = relu(resid + C + bias);
//         xf = relu(LN(x3)); column-reduce xf into embsum
template <int MODE>
__global__ __launch_bounds__(256) void gemm_ln(const __bf16* __restrict__ A,
                                               const __bf16* __restrict__ A2,
                                               const __bf16* __restrict__ A3,
                                               const __bf16* __restrict__ A4,
                                               const __bf16* __restrict__ W,
                                               const float* __restrict__ bias, int K,
                                               const __bf16* __restrict__ resid,
                                               const float* __restrict__ g,
                                               const float* __restrict__ bb,
                                               __bf16* __restrict__ out1,
                                               __bf16* __restrict__ out2,
                                               float* __restrict__ embsum) {
    __shared__ __bf16 As[64 * 64];     // 8KB
    __shared__ __bf16 Bs[256 * 64];    // 32KB
    __shared__ float cs[256];
    const int tid = threadIdx.x, w = tid >> 6, l = tid & 63;
    const int m0 = blockIdx.x * 64;
    const int quad = l >> 4, col15 = l & 15;
    const int lrow = l >> 3, pbs = l & 7;

    f32x4 acc[16];
    f32x4 zz = {0.f, 0.f, 0.f, 0.f};
    #pragma unroll
    for (int i = 0; i < 16; i++) acc[i] = zz;
    if (MODE == 1) { cs[tid] = 0.f; }

    // number of Y partial buffers for these 64 rows (uniform per block)
    int nsum = 1;
    if (MODE == 0) nsum = (((m0 & (Tc - 1)) >> 6) + 8) >> 3;   // 1..4
    const __bf16* Ys[4] = {A, A2, A3, A4};

    for (int kb = 0; kb < K; kb += 64) {
        if (MODE == 0) {
            bfx8 av[2];
            int rows[2], blks[2];
            #pragma unroll
            for (int it = 0; it < 2; it++) {
                int idx = it * 256 + tid;
                int row = idx >> 3, blk = idx & 7;
                rows[it] = row; blks[it] = blk;
                size_t off = (size_t)(m0 + row) * K + kb + blk * 8;
                bfx8 a1 = *(const bfx8*)(A + off);
                float tmp[8];
                #pragma unroll
                for (int jj = 0; jj < 8; jj++) tmp[jj] = (float)a1[jj];
                for (int j = 1; j < nsum; j++) {
                    bfx8 aj = *(const bfx8*)(Ys[j] + off);
                    #pragma unroll
                    for (int jj = 0; jj < 8; jj++) tmp[jj] += (float)aj[jj];
                }
                #pragma unroll
                for (int jj = 0; jj < 8; jj++) a1[jj] = (__bf16)tmp[jj];
                av[it] = a1;
            }
            __syncthreads();
            #pragma unroll
            for (int it = 0; it < 2; it++) {
                int row = rows[it];
                int pb = blks[it] ^ (row & 7);
                *(bfx8*)(As + row * 64 + pb * 8) = av[it];
            }
        } else {
            __syncthreads();
            #pragma unroll
            for (int it = 0; it < 2; it++) {
                int chunk = w * 2 + it;
                int row = chunk * 8 + lrow;
                int lb = pbs ^ (row & 7);
                gll16(A + (size_t)(m0 + row) * K + kb + lb * 8, As + chunk * 512);
            }
        }
        #pragma unroll
        for (int it = 0; it < 8; it++) {   // B: 32 chunks (all 256 n-rows)
            int chunk = w * 8 + it;
            int row = chunk * 8 + lrow;
            int lb = pbs ^ (row & 7);
            gll16(W + (size_t)row * K + kb + lb * 8, Bs + chunk * 512);
        }
        __syncthreads();
        #pragma unroll
        for (int ks = 0; ks < 2; ks++) {
            int arow = w * 16 + col15;
            int apb = (ks * 4 + quad) ^ (arow & 7);
            bfx8 af = *(const bfx8*)(As + arow * 64 + apb * 8);
            #pragma unroll
            for (int ct = 0; ct < 16; ct++) {
                int brow = ct * 16 + col15;
                int bpb = (ks * 4 + quad) ^ (brow & 7);
                bfx8 bf = *(const bfx8*)(Bs + brow * 64 + bpb * 8);
                acc[ct] = __builtin_amdgcn_mfma_f32_16x16x32_bf16(af, bf, acc[ct], 0, 0, 0);
            }
        }
    }
    __syncthreads();

    float xv[16][4];
    #pragma unroll
    for (int ct = 0; ct < 16; ct++) {
        int ng = ct * 16 + col15;
        float bsv = bias[ng];
        #pragma unroll
        for (int r = 0; r < 4; r++) {
            int mg = m0 + w * 16 + quad * 4 + r;
            float v = acc[ct][r] + bsv + (float)resid[(size_t)mg * 256 + ng];
            if (MODE == 1) v = fmaxf(v, 0.f);
            xv[ct][r] = v;
        }
    }
    if (MODE == 0) {
        #pragma unroll
        for (int ct = 0; ct < 16; ct++) {
            int ng = ct * 16 + col15;
            #pragma unroll
            for (int r = 0; r < 4; r++) {
                int mg = m0 + w * 16 + quad * 4 + r;
                out1[(size_t)mg * 256 + ng] = (__bf16)xv[ct][r];
            }
        }
    }
    float s1[4], s2[4];
    #pragma unroll
    for (int r = 0; r < 4; r++) {
        float a = 0.f, b2 = 0.f;
        #pragma unroll
        for (int ct = 0; ct < 16; ct++) { a += xv[ct][r]; b2 += xv[ct][r] * xv[ct][r]; }
        #pragma unroll
        for (int o = 1; o < 16; o <<= 1) { a += __shfl_xor(a, o, 64); b2 += __shfl_xor(b2, o, 64); }
        s1[r] = a; s2[r] = b2;
    }
    float colsum[16];
    #pragma unroll
    for (int ct = 0; ct < 16; ct++) colsum[ct] = 0.f;
    #pragma unroll
    for (int r = 0; r < 4; r++) {
        float mu = s1[r] * (1.f / 256.f);
        float var = s2[r] * (1.f / 256.f) - mu * mu;
        float rs = rsqrtf(var + 1e-5f);
        #pragma unroll
        for (int ct = 0; ct < 16; ct++) {
            int ng = ct * 16 + col15;
            float h = (xv[ct][r] - mu) * rs * g[ng] + bb[ng];
            if (MODE == 1) {
                colsum[ct] += fmaxf(h, 0.f);
            } else {
                int mg = m0 + w * 16 + quad * 4 + r;
                out2[(size_t)mg * 256 + ng] = (__bf16)h;
            }
        }
    }
    if (MODE == 1) {
        #pragma unroll
        for (int ct = 0; ct < 16; ct++) {
            colsum[ct] += __shfl_xor(colsum[ct], 16, 64);
            colsum[ct] += __shfl_xor(colsum[ct], 32, 64);
        }
        if (quad == 0) {
            #pragma unroll
            for (int ct = 0; ct < 16; ct++)
                atomicAdd(&cs[ct * 16 + col15], colsum[ct]);
        }
        __syncthreads();
        atomicAdd(&embsum[(m0 >> 11) * 256 + tid], cs[tid]);
    }
}

// ---------------- final: emb, logits, losses, outputs — FLOAT32 output ----------------
__global__ __launch_bounds__(256) void final_k(const float* embsum, const float* Yt,
                                               const float* head_w, const float* head_b,
                                               float* out) {
    __shared__ float semb[2048];
    __shared__ float slog[1072];
    int tid = threadIdx.x;
    for (int i = tid; i < 2048; i += 256) semb[i] = embsum[i] * (1.f / 2048.f);
    __syncthreads();
    float part1 = 0.f;
    for (int idx = tid; idx < 1072; idx += 256) {
        int b = idx / M2c, n = idx - b * M2c;
        float acc = head_b[n];
        const float* wn = head_w + (size_t)n * Ec;
        const float* e = semb + b * Ec;
        #pragma unroll 8
        for (int k = 0; k < Ec; k++) acc += e[k] * wn[k];
        acc = fmaxf(acc, 0.f);
        slog[idx] = acc;
        float d = acc - Yt[idx];
        part1 += d * d;
    }
    float part3 = 0.f;
    for (int idx = tid; idx < 1024; idx += 256) {
        int b = idx >> 7, i = idx & 127;
        float d = semb[b * Ec + i] - semb[b * Ec + 128 + i];
        part3 += d * d;
    }
    #pragma unroll
    for (int o = 32; o; o >>= 1) { part1 += __shfl_xor(part1, o, 64); part3 += __shfl_xor(part3, o, 64); }
    __shared__ float r1[4], r3[4];
    int w = tid >> 6;
    if ((tid & 63) == 0) { r1[w] = part1; r3[w] = part3; }
    __syncthreads();
    float l1 = sqrtf((r1[0] + r1[1] + r1[2] + r1[3]) / 1072.f);
    float l3 = sqrtf((r3[0] + r3[1] + r3[2] + r3[3]) / 1024.f);
    for (int idx = tid; idx < 1024; idx += 256) {
        int b = idx >> 7, i = idx & 127;
        out[idx]        = semb[b * Ec + i];
        out[1024 + idx] = semb[b * Ec + 128 + i];
    }
    if (tid == 0) {
        out[2048] = 50.f * l1 + l3;
        out[2049] = l1;
        out[2050] = l3;
    }
    for (int idx = tid; idx < 1072; idx += 256) out[2051 + idx] = slog[idx];
}

extern "C" void kernel_launch(void* const* d_in, const int* in_sizes, int n_in,
                              void* d_out, int out_size, void* d_ws, size_t ws_size,
                              hipStream_t stream) {
    const float* X        = (const float*)d_in[0];
    const float* Yt       = (const float*)d_in[1];
    const float* wpe      = (const float*)d_in[2];
    const float* ln1_g    = (const float*)d_in[3];
    const float* ln1_b    = (const float*)d_in[4];
    const float* attn_w   = (const float*)d_in[5];
    const float* attn_b   = (const float*)d_in[6];
    const float* apw      = (const float*)d_in[7];
    const float* apb      = (const float*)d_in[8];
    const float* ln2_g    = (const float*)d_in[9];
    const float* ln2_b    = (const float*)d_in[10];
    const float* fcw      = (const float*)d_in[11];
    const float* fcb      = (const float*)d_in[12];
    const float* mpw      = (const float*)d_in[13];
    const float* mpb      = (const float*)d_in[14];
    const float* lnf_g    = (const float*)d_in[15];
    const float* lnf_b    = (const float*)d_in[16];
    const float* head_w   = (const float*)d_in[17];
    const float* head_b   = (const float*)d_in[18];

    char* ws = (char*)d_ws;
    const size_t MB = 1048576;
    __bf16* xres   = (__bf16*)(ws + 0 * MB);    // 8 MB
    __bf16* hb     = (__bf16*)(ws + 8 * MB);    // 8 MB; later Y3
    __bf16* Qb     = (__bf16*)(ws + 16 * MB);   // 8 MB; later x2
    __bf16* Kb     = (__bf16*)(ws + 24 * MB);   // 8 MB; later h2
    __bf16* Vb     = (__bf16*)(ws + 32 * MB);   // 8 MB; later Y4
    __bf16* Vt     = (__bf16*)(ws + 40 * MB);   // 8 MB
    __bf16* Y1     = (__bf16*)(ws + 48 * MB);   // 8 MB
    __bf16* Y2     = (__bf16*)(ws + 56 * MB);   // 8 MB
    __bf16* fcout  = (__bf16*)(ws + 64 * MB);   // 16 MB
    __bf16* wb     = (__bf16*)(ws + 80 * MB);   // 1 MB
    float*  embsum = (float*)(ws + 81 * MB);    // 8 KB

    __bf16* x2   = Qb;     // Qb dead after attn
    __bf16* h2   = Kb;     // Kb dead after attn
    __bf16* Y3   = hb;     // hb dead after gemm0
    __bf16* Y4   = Vb;     // Vb dead after transpose

    __bf16* wqkv = wb;
    __bf16* wap  = wb + 196608;
    __bf16* wfc  = wb + 262144;
    __bf16* wmp  = wb + 393216;

    prep_k<<<2048, 256, 0, stream>>>(attn_w, apw, fcw, mpw, wb, embsum);
    embed_ln_k<<<Mrows, 256, 0, stream>>>(X, wpe, ln1_g, ln1_b, xres, hb);
    gemm_bt<0><<<dim3(6, 128), 256, 0, stream>>>(hb, wqkv, attn_b, 768, 256,
                                                 nullptr, Qb, Kb, Vb);
    transpose_v<<<dim3(32, 2, 16), 256, 0, stream>>>((const unsigned short*)Vb, (unsigned short*)Vt);
    attn6_k<<<1280, 256, 0, stream>>>(Qb, Kb, Vt, Y1, Y2, Y3, Y4);
    gemm_ln<0><<<256, 256, 0, stream>>>(Y1, Y2, Y3, Y4, wap, apb, 256, xres, ln2_g, ln2_b,
                                        x2, h2, nullptr);
    gemm_bt<2><<<dim3(4, 128), 256, 0, stream>>>(h2, wfc, fcb, 512, 256,
                                                 fcout, nullptr, nullptr, nullptr);
    gemm_ln<1><<<256, 256, 0, stream>>>(fcout, nullptr, nullptr, nullptr, wmp, mpb, 512,
                                        x2, lnf_g, lnf_b, nullptr, nullptr, embsum);
    final_k<<<1, 256, 0, stream>>>(embsum, Yt, head_w, head_b, (float*)d_out);
}

// Round 9
// 250.397 us; speedup vs baseline: 1.1444x; 1.0247x over previous
//
#include <hip/hip_runtime.h>
#include <hip/hip_bf16.h>

// Problem constants
#define Bc 8
#define Tc 2048
#define Ec 256
#define Hc 2
#define HDc 128
#define Mrows (Bc*Tc)          // 16384
#define M2c 134

using bfx8  = __attribute__((ext_vector_type(8))) __bf16;
using f32x4 = __attribute__((ext_vector_type(4))) float;

__device__ __forceinline__ void gll16(const __bf16* g, __bf16* lds) {
    __builtin_amdgcn_global_load_lds(
        (const __attribute__((address_space(1))) unsigned int*)g,
        (__attribute__((address_space(3))) unsigned int*)lds, 16, 0, 0);
}

// ---------------- embed + relu + LN1, fused weight-conversion + embsum zero ----------------
__global__ __launch_bounds__(256) void embed_prep_k(const float* X, const float* wpe,
                                                    const float* g, const float* bb,
                                                    const float* attn_w, const float* apw,
                                                    const float* fcw, const float* mpw,
                                                    __bf16* wb, float* embsum,
                                                    __bf16* xres, __bf16* hb) {
    int m = blockIdx.x;
    int e = threadIdx.x;
    // side-duty: weight conversion (blocks 0..2047) and embsum zeroing (blocks 0..7)
    if (m < 2048) {
        int i = m * 256 + e;
        if (i < 196608)       wb[i] = (__bf16)attn_w[i];
        else if (i < 262144)  wb[i] = (__bf16)apw[i - 196608];
        else if (i < 393216)  wb[i] = (__bf16)fcw[i - 262144];
        else                  wb[i] = (__bf16)mpw[i - 393216];
        if (m < 8) embsum[m * 256 + e] = 0.f;
    }
    int t = m & (Tc - 1);
    float v = X[(size_t)m * Ec + e] + wpe[(size_t)t * Ec + e] + wpe[(size_t)(t >= 1024) * Ec + e];
    v = fmaxf(v, 0.f);
    xres[(size_t)m * Ec + e] = (__bf16)v;
    float s1 = v, s2 = v * v;
    #pragma unroll
    for (int o = 32; o; o >>= 1) { s1 += __shfl_xor(s1, o, 64); s2 += __shfl_xor(s2, o, 64); }
    __shared__ float a1[4], a2[4];
    int w = threadIdx.x >> 6;
    if ((threadIdx.x & 63) == 0) { a1[w] = s1; a2[w] = s2; }
    __syncthreads();
    float m1 = (a1[0] + a1[1] + a1[2] + a1[3]) * (1.f / 256.f);
    float m2 = (a2[0] + a2[1] + a2[2] + a2[3]) * (1.f / 256.f);
    float r = rsqrtf(m2 - m1 * m1 + 1e-5f);
    hb[(size_t)m * Ec + e] = (__bf16)((v - m1) * r * g[e] + bb[e]);
}

// ---------------- B^T GEMM (128x128 tile): qkv scatter epilogue ----------------
__global__ __launch_bounds__(256) void gemm_qkv(const __bf16* __restrict__ A,
                                                const __bf16* __restrict__ Bw,
                                                const float* __restrict__ bias,
                                                __bf16* __restrict__ Qb,
                                                __bf16* __restrict__ Kb,
                                                __bf16* __restrict__ Vb) {
    const int K = 256;
    __shared__ __bf16 As[128 * 64];
    __shared__ __bf16 Bs[128 * 64];
    const int tid = threadIdx.x, w = tid >> 6, l = tid & 63;
    const int m0 = blockIdx.y * 128, n0 = blockIdx.x * 128;
    const int wr = w >> 1, wc = w & 1;
    const int quad = l >> 4, col15 = l & 15;

    f32x4 acc[4][4];
    f32x4 zz = {0.f, 0.f, 0.f, 0.f};
    #pragma unroll
    for (int i = 0; i < 4; i++)
        #pragma unroll
        for (int j = 0; j < 4; j++) acc[i][j] = zz;

    const int lrow = l >> 3;
    const int pbs  = l & 7;

    for (int kb = 0; kb < K; kb += 64) {
        #pragma unroll
        for (int it = 0; it < 4; it++) {
            int chunk = w * 4 + it;
            int row = chunk * 8 + lrow;
            int lb = pbs ^ (row & 7);
            gll16(A  + (size_t)(m0 + row) * K + kb + lb * 8, As + chunk * 512);
            gll16(Bw + (size_t)(n0 + row) * K + kb + lb * 8, Bs + chunk * 512);
        }
        __syncthreads();
        #pragma unroll
        for (int ks = 0; ks < 2; ks++) {
            bfx8 af[4], bfr[4];
            #pragma unroll
            for (int rt = 0; rt < 4; rt++) {
                int row = wr * 64 + rt * 16 + col15;
                int pb = (ks * 4 + quad) ^ (row & 7);
                af[rt] = *(const bfx8*)(As + row * 64 + pb * 8);
            }
            #pragma unroll
            for (int ct = 0; ct < 4; ct++) {
                int row = wc * 64 + ct * 16 + col15;
                int pb = (ks * 4 + quad) ^ (row & 7);
                bfr[ct] = *(const bfx8*)(Bs + row * 64 + pb * 8);
            }
            #pragma unroll
            for (int rt = 0; rt < 4; rt++)
                #pragma unroll
                for (int ct = 0; ct < 4; ct++)
                    acc[rt][ct] = __builtin_amdgcn_mfma_f32_16x16x32_bf16(af[rt], bfr[ct], acc[rt][ct], 0, 0, 0);
        }
        __syncthreads();
    }

    #pragma unroll
    for (int rt = 0; rt < 4; rt++)
        #pragma unroll
        for (int ct = 0; ct < 4; ct++) {
            int mgb = m0 + wr * 64 + rt * 16 + quad * 4;
            int ng  = n0 + wc * 64 + ct * 16 + col15;
            float bsv = bias[ng];
            #pragma unroll
            for (int r = 0; r < 4; r++) {
                float val = fmaxf(acc[rt][ct][r] + bsv, 0.f);
                int mg = mgb + r;
                int sel = ng >> 8;
                int hh = (ng >> 7) & 1;
                int d = ng & 127;
                int bb = mg >> 11, tt = mg & (Tc - 1);
                size_t idx = ((size_t)((bb * 2 + hh) * Tc + tt)) * HDc + d;
                __bf16 bv = (__bf16)val;
                if (sel == 0) Qb[idx] = bv;
                else if (sel == 1) Kb[idx] = bv;
                else Vb[idx] = bv;
            }
        }
}

// ---------------- transpose V -> Vt[bh][d][t] ----------------
__global__ __launch_bounds__(256) void transpose_v(const unsigned short* Vb, unsigned short* Vt) {
    __shared__ unsigned short tile[64][66];
    int kt = blockIdx.x, dt = blockIdx.y, bh = blockIdx.z;
    int tid = threadIdx.x;
    int k0 = kt * 64, d0 = dt * 64;
    int rr = tid >> 4, cc = (tid & 15) * 4;
    #pragma unroll
    for (int p = 0; p < 4; p++) {
        int k = p * 16 + rr;
        const unsigned short* src = Vb + ((size_t)(bh * Tc + k0 + k)) * HDc + d0 + cc;
        ushort4 vv = *(const ushort4*)src;
        tile[k][cc] = vv.x; tile[k][cc + 1] = vv.y; tile[k][cc + 2] = vv.z; tile[k][cc + 3] = vv.w;
    }
    __syncthreads();
    #pragma unroll
    for (int p = 0; p < 4; p++) {
        int d = p * 16 + rr;
        unsigned short* dst = Vt + ((size_t)(bh * HDc + d0 + d)) * Tc + k0 + cc;
        ushort4 ov;
        ov.x = tile[cc][d]; ov.y = tile[cc + 1][d]; ov.z = tile[cc + 2][d]; ov.w = tile[cc + 3][d];
        *(ushort4*)dst = ov;
    }
}

// ---------------- causal relu attention v6 (unchanged from R8) ----------------
__global__ __launch_bounds__(256, 4) void attn6_k(const __bf16* __restrict__ Qb,
                                                  const __bf16* __restrict__ Kb,
                                                  const __bf16* __restrict__ Vt,
                                                  __bf16* __restrict__ Y1,
                                                  __bf16* __restrict__ Y2,
                                                  __bf16* __restrict__ Y3,
                                                  __bf16* __restrict__ Y4) {
    __shared__ __bf16 Ks[64 * 128];   // 16KB
    __shared__ __bf16 Vs[128 * 64];   // 16KB
    __shared__ __bf16 Ss[64 * 64];    // 8KB
    int bid = blockIdx.x;             // 0..1279
    int lane8 = bid & 7;
    int s = bid >> 3;                 // 0..159
    int bh = ((s & 1) << 3) | lane8;
    int f = s >> 1;                   // 0..79
    int qt, ch;
    if (f < 8)       { qt = f;                    ch = 0; }
    else if (f < 24) { qt = 8 + ((f - 8) >> 1);   ch = (f - 8) & 1; }
    else if (f < 48) { int r = f - 24; int d3 = r / 3; qt = 16 + d3; ch = r - 3 * d3; }
    else             { int r = f - 48; qt = 24 + (r >> 2); ch = r & 3; }
    int Q0 = qt * 64;
    int kts = ch * 8;
    int kte = min(kts + 8, qt + 1);

    int tid = threadIdx.x, w = tid >> 6, l = tid & 63;
    int quad = l >> 4, col15 = l & 15;
    const int lrowK = l >> 4, pbsK = l & 15;
    const int lrowV = l >> 3, pbsV = l & 7;

    #pragma unroll
    for (int it = 0; it < 4; it++) {
        int chunk = w * 4 + it;
        int row = chunk * 4 + lrowK;
        int lb = pbsK ^ (row & 7);
        gll16(Qb + ((size_t)(bh * Tc + Q0 + row)) * HDc + lb * 8, Ks + chunk * 512);
    }
    __syncthreads();
    bfx8 qf[4];
    #pragma unroll
    for (int ks = 0; ks < 4; ks++) {
        int row = w * 16 + col15;
        int pb = (ks * 4 + quad) ^ (row & 7);
        qf[ks] = *(const bfx8*)(Ks + row * 128 + pb * 8);
    }

    f32x4 zz = {0.f, 0.f, 0.f, 0.f};
    f32x4 yacc[8];
    #pragma unroll
    for (int i = 0; i < 8; i++) yacc[i] = zz;

    for (int kt = kts; kt < kte; kt++) {
        __syncthreads();
        #pragma unroll
        for (int it = 0; it < 4; it++) {
            int chunk = w * 4 + it;
            int rowK = chunk * 4 + lrowK;
            int lbK = pbsK ^ (rowK & 7);
            gll16(Kb + ((size_t)(bh * Tc + kt * 64 + rowK)) * HDc + lbK * 8, Ks + chunk * 512);
            int rowV = chunk * 8 + lrowV;
            int lbV = pbsV ^ (rowV & 7);
            gll16(Vt + ((size_t)(bh * HDc + rowV)) * Tc + kt * 64 + lbV * 8, Vs + chunk * 512);
        }
        __syncthreads();

        f32x4 sacc[4];
        #pragma unroll
        for (int i = 0; i < 4; i++) sacc[i] = zz;
        #pragma unroll
        for (int ks = 0; ks < 4; ks++) {
            #pragma unroll
            for (int ct = 0; ct < 4; ct++) {
                int row = ct * 16 + col15;
                int pb = (ks * 4 + quad) ^ (row & 7);
                bfx8 kf = *(const bfx8*)(Ks + row * 128 + pb * 8);
                sacc[ct] = __builtin_amdgcn_mfma_f32_16x16x32_bf16(qf[ks], kf, sacc[ct], 0, 0, 0);
            }
        }

        #pragma unroll
        for (int ct = 0; ct < 4; ct++) {
            int kl = ct * 16 + col15;
            int kg = kt * 64 + kl;
            int blk = kl >> 3, off = kl & 7;
            #pragma unroll
            for (int r = 0; r < 4; r++) {
                int qlw = w * 16 + quad * 4 + r;
                float val = (kg <= Q0 + qlw) ? fmaxf(sacc[ct][r], 0.f) : 0.f;
                int pb = blk ^ (qlw & 7);
                Ss[qlw * 64 + pb * 8 + off] = (__bf16)val;
            }
        }

        #pragma unroll
        for (int ks = 0; ks < 2; ks++) {
            int rowS = w * 16 + col15;
            int pbS = (ks * 4 + quad) ^ (rowS & 7);
            bfx8 sf = *(const bfx8*)(Ss + rowS * 64 + pbS * 8);
            #pragma unroll
            for (int dt = 0; dt < 8; dt++) {
                int row = dt * 16 + col15;
                int pb = (ks * 4 + quad) ^ (row & 7);
                bfx8 vf = *(const bfx8*)(Vs + row * 64 + pb * 8);
                yacc[dt] = __builtin_amdgcn_mfma_f32_16x16x32_bf16(sf, vf, yacc[dt], 0, 0, 0);
            }
        }
    }

    __bf16* Yp = (ch == 0) ? Y1 : (ch == 1) ? Y2 : (ch == 2) ? Y3 : Y4;
    int b = bh >> 1, h = bh & 1;
    const float sc = 0.08838834764831845f;  // 1/sqrt(128)
    #pragma unroll
    for (int dt = 0; dt < 8; dt++) {
        int d = dt * 16 + col15;
        #pragma unroll
        for (int r = 0; r < 4; r++) {
            int q = Q0 + w * 16 + quad * 4 + r;
            Yp[((size_t)(b * Tc + q)) * Ec + h * HDc + d] = (__bf16)(yacc[dt][r] * sc);
        }
    }
}

// ---------------- MEGA: attnproj + LN2 + fc + mlpproj + LNf + column-reduce ----------------
// 64 rows per block, grid 256. The whole post-attention chain is row-local:
// x2 stays in VGPRs, h2 / fc-out stay in LDS. Writes ONLY embsum atomics to HBM.
// LDS: h2s 32KB + fc64 64KB + Bs 32KB + cs 1KB = 129KB.
__global__ __launch_bounds__(256, 1) void mega_k(const __bf16* __restrict__ Y1,
                                                 const __bf16* __restrict__ Y2,
                                                 const __bf16* __restrict__ Y3,
                                                 const __bf16* __restrict__ Y4,
                                                 const __bf16* __restrict__ wap,
                                                 const float* __restrict__ apb,
                                                 const __bf16* __restrict__ xres,
                                                 const float* __restrict__ ln2_g,
                                                 const float* __restrict__ ln2_b,
                                                 const __bf16* __restrict__ wfc,
                                                 const float* __restrict__ fcb,
                                                 const __bf16* __restrict__ wmp,
                                                 const float* __restrict__ mpb,
                                                 const float* __restrict__ lnf_g,
                                                 const float* __restrict__ lnf_b,
                                                 float* __restrict__ embsum) {
    __shared__ __bf16 h2s[4 * 4096];    // 32KB: 4 panels of 64 rows x 64 cols
    __shared__ __bf16 fc64[8 * 4096];   // 64KB: 8 panels (also aliases As in P1)
    __shared__ __bf16 Bs[256 * 64];     // 32KB
    __shared__ float cs[256];
    const int tid = threadIdx.x, w = tid >> 6, l = tid & 63;
    const int m0 = blockIdx.x * 64;
    const int quad = l >> 4, col15 = l & 15;
    const int lrow = l >> 3, pbs = l & 7;
    f32x4 zz = {0.f, 0.f, 0.f, 0.f};
    cs[tid] = 0.f;

    int nsum = (((m0 & (Tc - 1)) >> 6) + 8) >> 3;   // 1..4 Y-partials
    const __bf16* Ys[4] = {Y1, Y2, Y3, Y4};
    __bf16* As = fc64;   // P1 A-staging aliases fc64 (dead until P2 epilogue)

    f32x4 acc[16];
    #pragma unroll
    for (int i = 0; i < 16; i++) acc[i] = zz;

    // ---- P1: attnproj C = (ΣY) @ wap^T ----
    for (int kb = 0; kb < 256; kb += 64) {
        bfx8 av[2]; int rows[2], blks[2];
        #pragma unroll
        for (int it = 0; it < 2; it++) {
            int idx = it * 256 + tid;
            int row = idx >> 3, blk = idx & 7;
            rows[it] = row; blks[it] = blk;
            size_t off = (size_t)(m0 + row) * 256 + kb + blk * 8;
            bfx8 a1 = *(const bfx8*)(Y1 + off);
            float tmp[8];
            #pragma unroll
            for (int jj = 0; jj < 8; jj++) tmp[jj] = (float)a1[jj];
            for (int j = 1; j < nsum; j++) {
                bfx8 aj = *(const bfx8*)(Ys[j] + off);
                #pragma unroll
                for (int jj = 0; jj < 8; jj++) tmp[jj] += (float)aj[jj];
            }
            #pragma unroll
            for (int jj = 0; jj < 8; jj++) a1[jj] = (__bf16)tmp[jj];
            av[it] = a1;
        }
        __syncthreads();
        #pragma unroll
        for (int it = 0; it < 2; it++) {
            int row = rows[it];
            int pb = blks[it] ^ (row & 7);
            *(bfx8*)(As + row * 64 + pb * 8) = av[it];
        }
        #pragma unroll
        for (int it = 0; it < 8; it++) {
            int chunk = w * 8 + it;
            int row = chunk * 8 + lrow;
            int lb = pbs ^ (row & 7);
            gll16(wap + (size_t)row * 256 + kb + lb * 8, Bs + chunk * 512);
        }
        __syncthreads();
        #pragma unroll
        for (int ks = 0; ks < 2; ks++) {
            int arow = w * 16 + col15;
            int apbk = (ks * 4 + quad) ^ (arow & 7);
            bfx8 af = *(const bfx8*)(As + arow * 64 + apbk * 8);
            #pragma unroll
            for (int ct = 0; ct < 16; ct++) {
                int brow = ct * 16 + col15;
                int bpb = (ks * 4 + quad) ^ (brow & 7);
                bfx8 bf = *(const bfx8*)(Bs + brow * 64 + bpb * 8);
                acc[ct] = __builtin_amdgcn_mfma_f32_16x16x32_bf16(af, bf, acc[ct], 0, 0, 0);
            }
        }
    }

    // ---- P1 epilogue: x2 = resid + C + bias (keep f32 in VGPR); h2 = LN2(x2) -> LDS ----
    float xv[16][4];
    #pragma unroll
    for (int ct = 0; ct < 16; ct++) {
        int ng = ct * 16 + col15;
        float bsv = apb[ng];
        #pragma unroll
        for (int r = 0; r < 4; r++) {
            int mg = m0 + w * 16 + quad * 4 + r;
            xv[ct][r] = acc[ct][r] + bsv + (float)xres[(size_t)mg * 256 + ng];
        }
    }
    {
        float s1[4], s2[4];
        #pragma unroll
        for (int r = 0; r < 4; r++) {
            float a = 0.f, b2 = 0.f;
            #pragma unroll
            for (int ct = 0; ct < 16; ct++) { a += xv[ct][r]; b2 += xv[ct][r] * xv[ct][r]; }
            #pragma unroll
            for (int o = 1; o < 16; o <<= 1) { a += __shfl_xor(a, o, 64); b2 += __shfl_xor(b2, o, 64); }
            s1[r] = a; s2[r] = b2;
        }
        #pragma unroll
        for (int r = 0; r < 4; r++) {
            float mu = s1[r] * (1.f / 256.f);
            float var = s2[r] * (1.f / 256.f) - mu * mu;
            float rs = rsqrtf(var + 1e-5f);
            int row = w * 16 + quad * 4 + r;
            #pragma unroll
            for (int ct = 0; ct < 16; ct++) {
                int ng = ct * 16 + col15;
                float h = (xv[ct][r] - mu) * rs * ln2_g[ng] + ln2_b[ng];
                int panel = ng >> 6, c = ng & 63;
                h2s[panel * 4096 + row * 64 + ((c >> 3) ^ (row & 7)) * 8 + (c & 7)] = (__bf16)h;
            }
        }
    }
    // h2s rows are same-wave-private; P2's staging barriers cover visibility.

    // ---- P2: fc = relu(h2 @ wfc^T + fcb), two 256-col halves -> fc64 LDS ----
    for (int half = 0; half < 2; half++) {
        f32x4 acc2[16];
        #pragma unroll
        for (int i = 0; i < 16; i++) acc2[i] = zz;
        for (int kb = 0; kb < 256; kb += 64) {
            __syncthreads();
            #pragma unroll
            for (int it = 0; it < 8; it++) {
                int chunk = w * 8 + it;
                int row = chunk * 8 + lrow;
                int lb = pbs ^ (row & 7);
                gll16(wfc + (size_t)(half * 256 + row) * 256 + kb + lb * 8, Bs + chunk * 512);
            }
            __syncthreads();
            int panel = kb >> 6;
            #pragma unroll
            for (int ks = 0; ks < 2; ks++) {
                int arow = w * 16 + col15;
                int apbk = (ks * 4 + quad) ^ (arow & 7);
                bfx8 af = *(const bfx8*)(h2s + panel * 4096 + arow * 64 + apbk * 8);
                #pragma unroll
                for (int ct = 0; ct < 16; ct++) {
                    int brow = ct * 16 + col15;
                    int bpb = (ks * 4 + quad) ^ (brow & 7);
                    bfx8 bf = *(const bfx8*)(Bs + brow * 64 + bpb * 8);
                    acc2[ct] = __builtin_amdgcn_mfma_f32_16x16x32_bf16(af, bf, acc2[ct], 0, 0, 0);
                }
            }
        }
        #pragma unroll
        for (int ct = 0; ct < 16; ct++) {
            int col = half * 256 + ct * 16 + col15;
            float bsv = fcb[col];
            int panel = col >> 6, c = col & 63;
            #pragma unroll
            for (int r = 0; r < 4; r++) {
                int row = w * 16 + quad * 4 + r;
                float val = fmaxf(acc2[ct][r] + bsv, 0.f);
                fc64[panel * 4096 + row * 64 + ((c >> 3) ^ (row & 7)) * 8 + (c & 7)] = (__bf16)val;
            }
        }
    }

    // ---- P3: mlpproj C = fc64 @ wmp^T ----
    #pragma unroll
    for (int i = 0; i < 16; i++) acc[i] = zz;
    for (int kb = 0; kb < 512; kb += 64) {
        __syncthreads();
        #pragma unroll
        for (int it = 0; it < 8; it++) {
            int chunk = w * 8 + it;
            int row = chunk * 8 + lrow;
            int lb = pbs ^ (row & 7);
            gll16(wmp + (size_t)row * 512 + kb + lb * 8, Bs + chunk * 512);
        }
        __syncthreads();
        int panel = kb >> 6;
        #pragma unroll
        for (int ks = 0; ks < 2; ks++) {
            int arow = w * 16 + col15;
            int apbk = (ks * 4 + quad) ^ (arow & 7);
            bfx8 af = *(const bfx8*)(fc64 + panel * 4096 + arow * 64 + apbk * 8);
            #pragma unroll
            for (int ct = 0; ct < 16; ct++) {
                int brow = ct * 16 + col15;
                int bpb = (ks * 4 + quad) ^ (brow & 7);
                bfx8 bf = *(const bfx8*)(Bs + brow * 64 + bpb * 8);
                acc[ct] = __builtin_amdgcn_mfma_f32_16x16x32_bf16(af, bf, acc[ct], 0, 0, 0);
            }
        }
    }

    // ---- P4: x3 = relu(x2 + C + mpb); LNf; xf = relu(LN); column-reduce ----
    #pragma unroll
    for (int ct = 0; ct < 16; ct++) {
        int ng = ct * 16 + col15;
        float bsv = mpb[ng];
        #pragma unroll
        for (int r = 0; r < 4; r++)
            xv[ct][r] = fmaxf(acc[ct][r] + bsv + xv[ct][r], 0.f);
    }
    float s1[4], s2[4];
    #pragma unroll
    for (int r = 0; r < 4; r++) {
        float a = 0.f, b2 = 0.f;
        #pragma unroll
        for (int ct = 0; ct < 16; ct++) { a += xv[ct][r]; b2 += xv[ct][r] * xv[ct][r]; }
        #pragma unroll
        for (int o = 1; o < 16; o <<= 1) { a += __shfl_xor(a, o, 64); b2 += __shfl_xor(b2, o, 64); }
        s1[r] = a; s2[r] = b2;
    }
    float colsum[16];
    #pragma unroll
    for (int ct = 0; ct < 16; ct++) colsum[ct] = 0.f;
    #pragma unroll
    for (int r = 0; r < 4; r++) {
        float mu = s1[r] * (1.f / 256.f);
        float var = s2[r] * (1.f / 256.f) - mu * mu;
        float rs = rsqrtf(var + 1e-5f);
        #pragma unroll
        for (int ct = 0; ct < 16; ct++) {
            int ng = ct * 16 + col15;
            float h = (xv[ct][r] - mu) * rs * lnf_g[ng] + lnf_b[ng];
            colsum[ct] += fmaxf(h, 0.f);
        }
    }
    #pragma unroll
    for (int ct = 0; ct < 16; ct++) {
        colsum[ct] += __shfl_xor(colsum[ct], 16, 64);
        colsum[ct] += __shfl_xor(colsum[ct], 32, 64);
    }
    if (quad == 0) {
        #pragma unroll
        for (int ct = 0; ct < 16; ct++)
            atomicAdd(&cs[ct * 16 + col15], colsum[ct]);
    }
    __syncthreads();
    atomicAdd(&embsum[(m0 >> 11) * 256 + tid], cs[tid]);
}

// ---------------- final: emb, logits, losses, outputs — FLOAT32 output ----------------
__global__ __launch_bounds__(256) void final_k(const float* embsum, const float* Yt,
                                               const float* head_w, const float* head_b,
                                               float* out) {
    __shared__ float semb[2048];
    __shared__ float slog[1072];
    int tid = threadIdx.x;
    for (int i = tid; i < 2048; i += 256) semb[i] = embsum[i] * (1.f / 2048.f);
    __syncthreads();
    float part1 = 0.f;
    for (int idx = tid; idx < 1072; idx += 256) {
        int b = idx / M2c, n = idx - b * M2c;
        float acc = head_b[n];
        const float* wn = head_w + (size_t)n * Ec;
        const float* e = semb + b * Ec;
        #pragma unroll 8
        for (int k = 0; k < Ec; k++) acc += e[k] * wn[k];
        acc = fmaxf(acc, 0.f);
        slog[idx] = acc;
        float d = acc - Yt[idx];
        part1 += d * d;
    }
    float part3 = 0.f;
    for (int idx = tid; idx < 1024; idx += 256) {
        int b = idx >> 7, i = idx & 127;
        float d = semb[b * Ec + i] - semb[b * Ec + 128 + i];
        part3 += d * d;
    }
    #pragma unroll
    for (int o = 32; o; o >>= 1) { part1 += __shfl_xor(part1, o, 64); part3 += __shfl_xor(part3, o, 64); }
    __shared__ float r1[4], r3[4];
    int w = tid >> 6;
    if ((tid & 63) == 0) { r1[w] = part1; r3[w] = part3; }
    __syncthreads();
    float l1 = sqrtf((r1[0] + r1[1] + r1[2] + r1[3]) / 1072.f);
    float l3 = sqrtf((r3[0] + r3[1] + r3[2] + r3[3]) / 1024.f);
    for (int idx = tid; idx < 1024; idx += 256) {
        int b = idx >> 7, i = idx & 127;
        out[idx]        = semb[b * Ec + i];
        out[1024 + idx] = semb[b * Ec + 128 + i];
    }
    if (tid == 0) {
        out[2048] = 50.f * l1 + l3;
        out[2049] = l1;
        out[2050] = l3;
    }
    for (int idx = tid; idx < 1072; idx += 256) out[2051 + idx] = slog[idx];
}

extern "C" void kernel_launch(void* const* d_in, const int* in_sizes, int n_in,
                              void* d_out, int out_size, void* d_ws, size_t ws_size,
                              hipStream_t stream) {
    const float* X        = (const float*)d_in[0];
    const float* Yt       = (const float*)d_in[1];
    const float* wpe      = (const float*)d_in[2];
    const float* ln1_g    = (const float*)d_in[3];
    const float* ln1_b    = (const float*)d_in[4];
    const float* attn_w   = (const float*)d_in[5];
    const float* attn_b   = (const float*)d_in[6];
    const float* apw      = (const float*)d_in[7];
    const float* apb      = (const float*)d_in[8];
    const float* ln2_g    = (const float*)d_in[9];
    const float* ln2_b    = (const float*)d_in[10];
    const float* fcw      = (const float*)d_in[11];
    const float* fcb      = (const float*)d_in[12];
    const float* mpw      = (const float*)d_in[13];
    const float* mpb      = (const float*)d_in[14];
    const float* lnf_g    = (const float*)d_in[15];
    const float* lnf_b    = (const float*)d_in[16];
    const float* head_w   = (const float*)d_in[17];
    const float* head_b   = (const float*)d_in[18];

    char* ws = (char*)d_ws;
    const size_t MB = 1048576;
    __bf16* xres   = (__bf16*)(ws + 0 * MB);    // 8 MB
    __bf16* hb     = (__bf16*)(ws + 8 * MB);    // 8 MB; later Y3
    __bf16* Qb     = (__bf16*)(ws + 16 * MB);   // 8 MB
    __bf16* Kb     = (__bf16*)(ws + 24 * MB);   // 8 MB
    __bf16* Vb     = (__bf16*)(ws + 32 * MB);   // 8 MB; later Y4
    __bf16* Vt     = (__bf16*)(ws + 40 * MB);   // 8 MB
    __bf16* Y1     = (__bf16*)(ws + 48 * MB);   // 8 MB
    __bf16* Y2     = (__bf16*)(ws + 56 * MB);   // 8 MB
    __bf16* wb     = (__bf16*)(ws + 64 * MB);   // 1 MB
    float*  embsum = (float*)(ws + 65 * MB);    // 8 KB

    __bf16* Y3 = hb;     // hb dead after gemm_qkv
    __bf16* Y4 = Vb;     // Vb dead after transpose_v

    __bf16* wqkv = wb;
    __bf16* wap  = wb + 196608;
    __bf16* wfc  = wb + 262144;
    __bf16* wmp  = wb + 393216;

    embed_prep_k<<<Mrows, 256, 0, stream>>>(X, wpe, ln1_g, ln1_b,
                                            attn_w, apw, fcw, mpw, wb, embsum, xres, hb);
    gemm_qkv<<<dim3(6, 128), 256, 0, stream>>>(hb, wqkv, attn_b, Qb, Kb, Vb);
    transpose_v<<<dim3(32, 2, 16), 256, 0, stream>>>((const unsigned short*)Vb, (unsigned short*)Vt);
    attn6_k<<<1280, 256, 0, stream>>>(Qb, Kb, Vt, Y1, Y2, Y3, Y4);
    mega_k<<<256, 256, 0, stream>>>(Y1, Y2, Y3, Y4, wap, apb, xres, ln2_g, ln2_b,
                                    wfc, fcb, wmp, mpb, lnf_g, lnf_b, embsum);
    final_k<<<1, 256, 0, stream>>>(embsum, Yt, head_w, head_b, (float*)d_out);
}